// Round 6
// baseline (234.218 us; speedup 1.0000x reference)
//
#include <hip/hip_runtime.h>
#include <math.h>

#define Hh 512
#define Ww 512
#define Bb 4
#define Ee 32
#define PLANE (Hh*Ww)        // 262144
#define NOFF 9
#define EC 8                 // e-values per block (4 chunks)

// ws layout (float indices)
#define WS_BLUR   0          // 262144 floats: blurred raw
#define WS_MIN    524304     // 16 uints
#define WS_MAX    524320     // 16 uints
#define WS_ACC    524336     // double accumulator (8B-aligned)
#define WS_CNT    524338     // uint finished-block counter

__device__ __constant__ int d_OH[NOFF] = {0,-1,-1,0,-2,-2,0,-3,-3};
__device__ __constant__ int d_OW[NOFF] = {-1,0,-1,-2,0,-2,-3,0,-3};

__device__ __forceinline__ void gload_lds16(const float* g, float* l){
    __builtin_amdgcn_global_load_lds(
        (const __attribute__((address_space(1))) void*)g,
        (__attribute__((address_space(3))) void*)l, 16, 0, 0);
}

// ---- fused 2D gaussian blur (sigma=1.2, r=5, edge-clamped), 32x32 tiles + halo
#define TS 32
#define HALO 5
__global__ __launch_bounds__(256) void k_blur(const float* __restrict__ raw,
                                              float* __restrict__ ws){
    __shared__ float sraw[TS+2*HALO][TS+2*HALO+1];
    __shared__ float shb [TS][TS+2*HALO+1];
    int tx = blockIdx.x & 15, ty = blockIdx.x >> 4;
    int r0 = ty*TS - HALO, c0 = tx*TS - HALO;

    double kd[11], s = 0.0;
    #pragma unroll
    for (int i = 0; i < 11; i++){
        double x = (double)(i - 5) / 1.2;
        kd[i] = exp(-0.5 * x * x);
        s += kd[i];
    }
    float w[11];
    #pragma unroll
    for (int i = 0; i < 11; i++) w[i] = (float)(kd[i] / s);

    for (int t = threadIdx.x; t < 42*42; t += 256){
        int rr = t / 42, cc = t - rr*42;
        int gr = min(max(r0+rr, 0), Hh-1);
        int gc = min(max(c0+cc, 0), Ww-1);
        sraw[rr][cc] = raw[gr*Ww + gc];
    }
    __syncthreads();
    for (int t = threadIdx.x; t < TS*42; t += 256){
        int rr = t / 42, cc = t - rr*42;
        float a = 0.f;
        #pragma unroll
        for (int i = 0; i < 11; i++) a += w[i] * sraw[rr+i][cc];
        shb[rr][cc] = a;
    }
    __syncthreads();
    for (int t = threadIdx.x; t < TS*TS; t += 256){
        int rr = t >> 5, cc = t & 31;
        float a = 0.f;
        #pragma unroll
        for (int i = 0; i < 11; i++) a += w[i] * shb[rr][cc+i];
        ws[WS_BLUR + (ty*TS+rr)*Ww + (tx*TS+cc)] = a;
    }
    if (blockIdx.x == 0){
        if (threadIdx.x < 16){
            ((unsigned int*)(ws + WS_MIN))[threadIdx.x] = 0x7F800000u;
            ((unsigned int*)(ws + WS_MAX))[threadIdx.x] = 0u;
        }
        if (threadIdx.x == 0){
            *(double*)(ws + WS_ACC) = 0.0;
            *(unsigned int*)(ws + WS_CNT) = 0u;
        }
    }
}

// per-offset min/max of d_i = |blur - rolled blur|
__global__ void k_minmax(float* __restrict__ ws){
    int idx = blockIdx.x * 512 + threadIdx.x;
    int h = idx >> 9, w = idx & 511;
    float bc = ws[WS_BLUR + idx];
    int lane = threadIdx.x & 63, wv = threadIdx.x >> 6;
    __shared__ float smn[8 * NOFF], smx[8 * NOFF];
    #pragma unroll
    for (int i = 0; i < NOFF; i++){
        int hn = (h + d_OH[i]) & (Hh-1);
        int wn = (w + d_OW[i]) & (Ww-1);
        float d = fabsf(bc - ws[WS_BLUR + hn * Ww + wn]);
        float mnv = d, mxv = d;
        for (int s = 32; s; s >>= 1){
            mnv = fminf(mnv, __shfl_xor(mnv, s));
            mxv = fmaxf(mxv, __shfl_xor(mxv, s));
        }
        if (lane == 0){ smn[wv * NOFF + i] = mnv; smx[wv * NOFF + i] = mxv; }
    }
    __syncthreads();
    if (threadIdx.x < NOFF){
        float mnv = smn[threadIdx.x], mxv = smx[threadIdx.x];
        for (int v = 1; v < 8; v++){
            mnv = fminf(mnv, smn[v * NOFF + threadIdx.x]);
            mxv = fmaxf(mxv, smx[v * NOFF + threadIdx.x]);
        }
        atomicMin((unsigned int*)(ws + WS_MIN) + threadIdx.x, __float_as_uint(mnv));
        atomicMax((unsigned int*)(ws + WS_MAX) + threadIdx.x, __float_as_uint(mxv));
    }
}

// fused loss, LDS-staged tf tiles.
// block = 512 thr, 4 rows x 512 cols of one batch, EC e-planes.
// grid = 4 batches x 4 e-chunks x 128 rowgroups = 2048
// NOTE: the csum term (sum_i c_i) must be counted ONCE per pixel; only the
// ec==0 block contributes it (R4 bug: every e-chunk added it -> 4x csum).
__global__ __launch_bounds__(512, 6)
void k_main(const float* __restrict__ E, const float* __restrict__ T,
            const float* __restrict__ mask, float* __restrict__ ws,
            float* __restrict__ out){
    __shared__ float sT[2][7*512];    // 2 x 14KB tf tile (rows h-3..h+3)

    int blk = blockIdx.x;
    int bb  = blk >> 9;               // batch
    int ec  = (blk >> 7) & 3;         // e-chunk
    int rg  = blk & 127;              // rowgroup
    int row4 = rg << 2;
    int e0  = ec * EC;

    int tid = threadIdx.x;
    int rq  = tid >> 7;               // 0..3 (wave-uniform)
    int wq  = tid & 127;
    int wv  = tid >> 6;               // wave 0..7
    int ln  = tid & 63;
    int hr  = row4 + rq;
    int c0  = wq << 2;
    int cl  = (c0 - 4) & 511;
    int pix = hr * Ww + c0;

    // ---- per-pixel coefficients c[j][i] from blurred raw + mask
    const float* bl = ws + WS_BLUR;
    float tb[4][8];
    #pragma unroll
    for (int r = 0; r < 4; r++){
        int rr = (hr - r) & 511;
        float4 l4 = *(const float4*)(bl + rr*Ww + cl);
        float4 o4 = *(const float4*)(bl + rr*Ww + c0);
        tb[r][0]=l4.x; tb[r][1]=l4.y; tb[r][2]=l4.z; tb[r][3]=l4.w;
        tb[r][4]=o4.x; tb[r][5]=o4.y; tb[r][6]=o4.z; tb[r][7]=o4.w;
    }
    const unsigned int* mnb = (const unsigned int*)(ws + WS_MIN);
    const unsigned int* mxb = (const unsigned int*)(ws + WS_MAX);
    float mn[NOFF], inv[NOFF];
    #pragma unroll
    for (int i = 0; i < NOFF; i++){
        mn[i]  = __uint_as_float(mnb[i]);
        inv[i] = 1.f / (__uint_as_float(mxb[i]) - mn[i]);
    }
    float c[4][NOFF];
    float acc[4];
    float csw = (ec == 0) ? 1.f : 0.f;   // count csum exactly once per pixel
    #pragma unroll
    for (int j = 0; j < 4; j++){
        float bc = tb[0][4+j];
        float d[NOFF];
        d[0] = fabsf(bc - tb[0][3+j]);
        d[1] = fabsf(bc - tb[1][4+j]);
        d[2] = fabsf(bc - tb[1][3+j]);
        d[3] = fabsf(bc - tb[0][2+j]);
        d[4] = fabsf(bc - tb[2][4+j]);
        d[5] = fabsf(bc - tb[2][2+j]);
        d[6] = fabsf(bc - tb[0][1+j]);
        d[7] = fabsf(bc - tb[3][4+j]);
        d[8] = fabsf(bc - tb[3][1+j]);
        acc[j] = 0.f;
        #pragma unroll
        for (int i = 0; i < NOFF; i++){
            float a = (d[i] - mn[i]) * inv[i];
            float mv = ((const float*)(mask + i * PLANE + pix))[j];
            c[j][i] = mv * (0.5f - a);
            acc[j] = fmaf(csw, c[j][i], acc[j]);
        }
    }

    const float* Tb = T + (size_t)bb * Ee * PLANE;
    const float* Eb = E + (size_t)bb * Ee * PLANE + pix;

    // stage 7 rows (14 chunks of 1KB) of plane e into sT[buf]
    auto STG = [&](int buf, int e){
        const float* Tp = Tb + (size_t)e * PLANE;
        int k = wv >> 1, half = (wv & 1) << 8;
        gload_lds16(Tp + ((row4 - 3 + k) & 511)*Ww + half + ln*4,
                    &sT[buf][k*512 + half]);
        if (wv < 6){
            int c2 = wv + 8, k2 = c2 >> 1, h2 = (c2 & 1) << 8;
            gload_lds16(Tp + ((row4 - 3 + k2) & 511)*Ww + h2 + ln*4,
                        &sT[buf][k2*512 + h2]);
        }
    };

    // compute one e-plane from LDS tile; own rows at tile rows 3+rq-delta
    auto CMP = [&](const float* tile, float4 ev4){
        float s0, s1, s2, s3;
        {   // delta 0: offsets (0,-1),(0,-2),(0,-3)
            const float* rp = tile + (3 + rq) * 512;
            float4 l4 = *(const float4*)(rp + cl);
            float4 o4 = *(const float4*)(rp + c0);
            float t[8] = {l4.x,l4.y,l4.z,l4.w, o4.x,o4.y,o4.z,o4.w};
            s0 = c[0][0]*t[3] ; s0 = fmaf(c[0][3], t[2], s0); s0 = fmaf(c[0][6], t[1], s0);
            s1 = c[1][0]*t[4] ; s1 = fmaf(c[1][3], t[3], s1); s1 = fmaf(c[1][6], t[2], s1);
            s2 = c[2][0]*t[5] ; s2 = fmaf(c[2][3], t[4], s2); s2 = fmaf(c[2][6], t[3], s2);
            s3 = c[3][0]*t[6] ; s3 = fmaf(c[3][3], t[5], s3); s3 = fmaf(c[3][6], t[4], s3);
        }
        {   // delta 1: offsets (-1,0),(-1,-1)
            const float* rp = tile + (2 + rq) * 512;
            float4 l4 = *(const float4*)(rp + cl);
            float4 o4 = *(const float4*)(rp + c0);
            float t[8] = {l4.x,l4.y,l4.z,l4.w, o4.x,o4.y,o4.z,o4.w};
            s0 = fmaf(c[0][1], t[4], s0); s0 = fmaf(c[0][2], t[3], s0);
            s1 = fmaf(c[1][1], t[5], s1); s1 = fmaf(c[1][2], t[4], s1);
            s2 = fmaf(c[2][1], t[6], s2); s2 = fmaf(c[2][2], t[5], s2);
            s3 = fmaf(c[3][1], t[7], s3); s3 = fmaf(c[3][2], t[6], s3);
        }
        {   // delta 2: offsets (-2,0),(-2,-2)
            const float* rp = tile + (1 + rq) * 512;
            float4 l4 = *(const float4*)(rp + cl);
            float4 o4 = *(const float4*)(rp + c0);
            float t[8] = {l4.x,l4.y,l4.z,l4.w, o4.x,o4.y,o4.z,o4.w};
            s0 = fmaf(c[0][4], t[4], s0); s0 = fmaf(c[0][5], t[2], s0);
            s1 = fmaf(c[1][4], t[5], s1); s1 = fmaf(c[1][5], t[3], s1);
            s2 = fmaf(c[2][4], t[6], s2); s2 = fmaf(c[2][5], t[4], s2);
            s3 = fmaf(c[3][4], t[7], s3); s3 = fmaf(c[3][5], t[5], s3);
        }
        {   // delta 3: offsets (-3,0),(-3,-3)
            const float* rp = tile + (0 + rq) * 512;
            float4 l4 = *(const float4*)(rp + cl);
            float4 o4 = *(const float4*)(rp + c0);
            float t[8] = {l4.x,l4.y,l4.z,l4.w, o4.x,o4.y,o4.z,o4.w};
            s0 = fmaf(c[0][7], t[4], s0); s0 = fmaf(c[0][8], t[1], s0);
            s1 = fmaf(c[1][7], t[5], s1); s1 = fmaf(c[1][8], t[2], s1);
            s2 = fmaf(c[2][7], t[6], s2); s2 = fmaf(c[2][8], t[3], s2);
            s3 = fmaf(c[3][7], t[7], s3); s3 = fmaf(c[3][8], t[4], s3);
        }
        acc[0] = fmaf(-ev4.x, s0, acc[0]);
        acc[1] = fmaf(-ev4.y, s1, acc[1]);
        acc[2] = fmaf(-ev4.z, s2, acc[2]);
        acc[3] = fmaf(-ev4.w, s3, acc[3]);
    };

    // double-buffered pipeline over EC e-planes
    int e = e0;
    STG(0, e);
    float4 eva = *(const float4*)(Eb + (size_t)e * PLANE);
    __syncthreads();
    #pragma unroll 1
    for (int ei = 0; ei < EC; ei += 2){
        bool last = (ei == EC - 2);
        STG(1, e + 1);
        float4 evb = *(const float4*)(Eb + (size_t)(e + 1) * PLANE);
        CMP(sT[0], eva);
        __syncthreads();
        if (!last){
            STG(0, e + 2);
            eva = *(const float4*)(Eb + (size_t)(e + 2) * PLANE);
        }
        CMP(sT[1], evb);
        __syncthreads();
        e += 2;
    }

    float part = acc[0] + acc[1] + acc[2] + acc[3];
    for (int s = 32; s; s >>= 1) part += __shfl_xor(part, s);
    __shared__ float sp[8];
    if (ln == 0) sp[wv] = part;
    __syncthreads();
    if (tid == 0){
        float bs = 0.f;
        #pragma unroll
        for (int v = 0; v < 8; v++) bs += sp[v];
        double* accp = (double*)(ws + WS_ACC);
        atomicAdd(accp, (double)bs);
        __threadfence();
        unsigned int done = atomicAdd((unsigned int*)(ws + WS_CNT), 1u);
        if (done == gridDim.x - 1){
            double v = atomicAdd(accp, 0.0);
            out[0] = (float)(v / (double)((size_t)Bb * PLANE));
        }
    }
}

extern "C" void kernel_launch(void* const* d_in, const int* in_sizes, int n_in,
                              void* d_out, int out_size, void* d_ws, size_t ws_size,
                              hipStream_t stream) {
    const float* embeds = (const float*)d_in[0];   // [4,32,512,512]
    const float* tf     = (const float*)d_in[1];   // [4,32,512,512]
    const float* raw    = (const float*)d_in[2];   // [1,1,512,512]
    const float* mask   = (const float*)d_in[3];   // [1,9,512,512]
    float* ws  = (float*)d_ws;
    float* out = (float*)d_out;

    k_blur  <<<256, 256, 0, stream>>>(raw, ws);
    k_minmax<<<PLANE/512, 512, 0, stream>>>(ws);
    k_main  <<<2048, 512, 0, stream>>>(embeds, tf, mask, ws, out);
}

// Round 7
// 155.989 us; speedup vs baseline: 1.5015x; 1.5015x over previous
//
#include <hip/hip_runtime.h>
#include <math.h>

#define Hh 512
#define Ww 512
#define Bb 4
#define Ee 32
#define PLANE (Hh*Ww)        // 262144
#define NOFF 9
#define EC 8                 // e-planes per block (4 e-chunks)

// ws layout (float indices)
#define WS_BLUR   0          // 262144 floats: blurred raw
#define WS_MIN    524304     // 16 uints
#define WS_MAX    524320     // 16 uints
#define WS_ACC    524336     // double accumulator (8B-aligned)
#define WS_CNT    524338     // uint finished-block counter

__device__ __constant__ int d_OH[NOFF] = {0,-1,-1,0,-2,-2,0,-3,-3};
__device__ __constant__ int d_OW[NOFF] = {-1,0,-1,-2,0,-2,-3,0,-3};

// ---- fused 2D gaussian blur (sigma=1.2, r=5, edge-clamped), 32x32 tiles + halo
#define TS 32
#define HALO 5
__global__ __launch_bounds__(256) void k_blur(const float* __restrict__ raw,
                                              float* __restrict__ ws){
    __shared__ float sraw[TS+2*HALO][TS+2*HALO+1];
    __shared__ float shb [TS][TS+2*HALO+1];
    int tx = blockIdx.x & 15, ty = blockIdx.x >> 4;
    int r0 = ty*TS - HALO, c0 = tx*TS - HALO;

    double kd[11], s = 0.0;
    #pragma unroll
    for (int i = 0; i < 11; i++){
        double x = (double)(i - 5) / 1.2;
        kd[i] = exp(-0.5 * x * x);
        s += kd[i];
    }
    float w[11];
    #pragma unroll
    for (int i = 0; i < 11; i++) w[i] = (float)(kd[i] / s);

    for (int t = threadIdx.x; t < 42*42; t += 256){
        int rr = t / 42, cc = t - rr*42;
        int gr = min(max(r0+rr, 0), Hh-1);
        int gc = min(max(c0+cc, 0), Ww-1);
        sraw[rr][cc] = raw[gr*Ww + gc];
    }
    __syncthreads();
    for (int t = threadIdx.x; t < TS*42; t += 256){
        int rr = t / 42, cc = t - rr*42;
        float a = 0.f;
        #pragma unroll
        for (int i = 0; i < 11; i++) a += w[i] * sraw[rr+i][cc];
        shb[rr][cc] = a;
    }
    __syncthreads();
    for (int t = threadIdx.x; t < TS*TS; t += 256){
        int rr = t >> 5, cc = t & 31;
        float a = 0.f;
        #pragma unroll
        for (int i = 0; i < 11; i++) a += w[i] * shb[rr][cc+i];
        ws[WS_BLUR + (ty*TS+rr)*Ww + (tx*TS+cc)] = a;
    }
    if (blockIdx.x == 0){
        if (threadIdx.x < 16){
            ((unsigned int*)(ws + WS_MIN))[threadIdx.x] = 0x7F800000u;
            ((unsigned int*)(ws + WS_MAX))[threadIdx.x] = 0u;
        }
        if (threadIdx.x == 0){
            *(double*)(ws + WS_ACC) = 0.0;
            *(unsigned int*)(ws + WS_CNT) = 0u;
        }
    }
}

// per-offset min/max of d_i = |blur - rolled blur|
__global__ void k_minmax(float* __restrict__ ws){
    int idx = blockIdx.x * 512 + threadIdx.x;
    int h = idx >> 9, w = idx & 511;
    float bc = ws[WS_BLUR + idx];
    int lane = threadIdx.x & 63, wv = threadIdx.x >> 6;
    __shared__ float smn[8 * NOFF], smx[8 * NOFF];
    #pragma unroll
    for (int i = 0; i < NOFF; i++){
        int hn = (h + d_OH[i]) & (Hh-1);
        int wn = (w + d_OW[i]) & (Ww-1);
        float d = fabsf(bc - ws[WS_BLUR + hn * Ww + wn]);
        float mnv = d, mxv = d;
        for (int s = 32; s; s >>= 1){
            mnv = fminf(mnv, __shfl_xor(mnv, s));
            mxv = fmaxf(mxv, __shfl_xor(mxv, s));
        }
        if (lane == 0){ smn[wv * NOFF + i] = mnv; smx[wv * NOFF + i] = mxv; }
    }
    __syncthreads();
    if (threadIdx.x < NOFF){
        float mnv = smn[threadIdx.x], mxv = smx[threadIdx.x];
        for (int v = 1; v < 8; v++){
            mnv = fminf(mnv, smn[v * NOFF + threadIdx.x]);
            mxv = fmaxf(mxv, smx[v * NOFF + threadIdx.x]);
        }
        atomicMin((unsigned int*)(ws + WS_MIN) + threadIdx.x, __float_as_uint(mnv));
        atomicMax((unsigned int*)(ws + WS_MAX) + threadIdx.x, __float_as_uint(mxv));
    }
}

// 9 independent float4 loads per e-plane, register double-buffered
struct TT { float4 l0,o0,l1,o1,l2,o2,l3,o3, ev; };

// fused loss: 512-thr blocks, 4 rows x 512 cols, 4 px/thread, EC e-planes.
// grid = 4 batches x 4 e-chunks x 128 rowgroups = 2048 (8 blocks/CU queued).
// csum term counted once per pixel: only ec==0 blocks add it (csw).
__global__ __launch_bounds__(512)
void k_main(const float* __restrict__ E, const float* __restrict__ T,
            const float* __restrict__ mask, float* __restrict__ ws,
            float* __restrict__ out){
    int blk = blockIdx.x;
    int bb  = blk >> 9;               // batch (block-uniform)
    int ec  = (blk >> 7) & 3;         // e-chunk
    int rg  = blk & 127;              // rowgroup
    int row4 = rg << 2;
    int e0  = ec * EC;

    int tid = threadIdx.x;
    int rq  = tid >> 7;               // 0..3
    int wq  = tid & 127;
    int wv  = tid >> 6;
    int ln  = tid & 63;
    int hr  = row4 + rq;
    int c0  = wq << 2;
    int cl  = (c0 - 4) & 511;
    int rr1 = (hr-1)&511, rr2 = (hr-2)&511, rr3 = (hr-3)&511;
    int pix = hr * Ww + c0;

    int ro0 = pix,         lo0 = hr*Ww + cl;
    int ro1 = rr1*Ww + c0, lo1 = rr1*Ww + cl;
    int ro2 = rr2*Ww + c0, lo2 = rr2*Ww + cl;
    int ro3 = rr3*Ww + c0, lo3 = rr3*Ww + cl;

    // ---- per-pixel coefficients c[j][i] from blurred raw + mask
    const float* bl = ws + WS_BLUR;
    float tb[4][8];
    {
        float4 v;
        v = *(const float4*)(bl + lo0); tb[0][0]=v.x; tb[0][1]=v.y; tb[0][2]=v.z; tb[0][3]=v.w;
        v = *(const float4*)(bl + ro0); tb[0][4]=v.x; tb[0][5]=v.y; tb[0][6]=v.z; tb[0][7]=v.w;
        v = *(const float4*)(bl + lo1); tb[1][0]=v.x; tb[1][1]=v.y; tb[1][2]=v.z; tb[1][3]=v.w;
        v = *(const float4*)(bl + ro1); tb[1][4]=v.x; tb[1][5]=v.y; tb[1][6]=v.z; tb[1][7]=v.w;
        v = *(const float4*)(bl + lo2); tb[2][0]=v.x; tb[2][1]=v.y; tb[2][2]=v.z; tb[2][3]=v.w;
        v = *(const float4*)(bl + ro2); tb[2][4]=v.x; tb[2][5]=v.y; tb[2][6]=v.z; tb[2][7]=v.w;
        v = *(const float4*)(bl + lo3); tb[3][0]=v.x; tb[3][1]=v.y; tb[3][2]=v.z; tb[3][3]=v.w;
        v = *(const float4*)(bl + ro3); tb[3][4]=v.x; tb[3][5]=v.y; tb[3][6]=v.z; tb[3][7]=v.w;
    }
    const unsigned int* mnb = (const unsigned int*)(ws + WS_MIN);
    const unsigned int* mxb = (const unsigned int*)(ws + WS_MAX);
    float mn[NOFF], inv[NOFF];
    #pragma unroll
    for (int i = 0; i < NOFF; i++){
        mn[i]  = __uint_as_float(mnb[i]);
        inv[i] = 1.f / (__uint_as_float(mxb[i]) - mn[i]);
    }
    float c[4][NOFF];
    float acc[4];
    float csw = (ec == 0) ? 1.f : 0.f;
    #pragma unroll
    for (int j = 0; j < 4; j++){
        float bc = tb[0][4+j];
        float d[NOFF];
        d[0] = fabsf(bc - tb[0][3+j]);
        d[1] = fabsf(bc - tb[1][4+j]);
        d[2] = fabsf(bc - tb[1][3+j]);
        d[3] = fabsf(bc - tb[0][2+j]);
        d[4] = fabsf(bc - tb[2][4+j]);
        d[5] = fabsf(bc - tb[2][2+j]);
        d[6] = fabsf(bc - tb[0][1+j]);
        d[7] = fabsf(bc - tb[3][4+j]);
        d[8] = fabsf(bc - tb[3][1+j]);
        acc[j] = 0.f;
        #pragma unroll
        for (int i = 0; i < NOFF; i++){
            float a = (d[i] - mn[i]) * inv[i];
            float mv = ((const float*)(mask + i * PLANE + pix))[j];
            c[j][i] = mv * (0.5f - a);
            acc[j] = fmaf(csw, c[j][i], acc[j]);
        }
    }

    const float* Tb = T + (size_t)bb * Ee * PLANE;
    const float* Eb = E + (size_t)bb * Ee * PLANE + pix;

    auto LD = [&](TT& d, int e){
        const float* Tp = Tb + (size_t)e * PLANE;
        d.l0 = *(const float4*)(Tp + lo0); d.o0 = *(const float4*)(Tp + ro0);
        d.l1 = *(const float4*)(Tp + lo1); d.o1 = *(const float4*)(Tp + ro1);
        d.l2 = *(const float4*)(Tp + lo2); d.o2 = *(const float4*)(Tp + ro2);
        d.l3 = *(const float4*)(Tp + lo3); d.o3 = *(const float4*)(Tp + ro3);
        d.ev = *(const float4*)(Eb + (size_t)e * PLANE);
    };
    auto CMP = [&](const TT& t){
        float t0[8] = {t.l0.x,t.l0.y,t.l0.z,t.l0.w, t.o0.x,t.o0.y,t.o0.z,t.o0.w};
        float t1[8] = {t.l1.x,t.l1.y,t.l1.z,t.l1.w, t.o1.x,t.o1.y,t.o1.z,t.o1.w};
        float t2[8] = {t.l2.x,t.l2.y,t.l2.z,t.l2.w, t.o2.x,t.o2.y,t.o2.z,t.o2.w};
        float t3[8] = {t.l3.x,t.l3.y,t.l3.z,t.l3.w, t.o3.x,t.o3.y,t.o3.z,t.o3.w};
        float ev[4] = {t.ev.x, t.ev.y, t.ev.z, t.ev.w};
        #pragma unroll
        for (int j = 0; j < 4; j++){
            float s =        c[j][0] * t0[3+j];
            s = fmaf(c[j][1], t1[4+j], s);
            s = fmaf(c[j][2], t1[3+j], s);
            s = fmaf(c[j][3], t0[2+j], s);
            s = fmaf(c[j][4], t2[4+j], s);
            s = fmaf(c[j][5], t2[2+j], s);
            s = fmaf(c[j][6], t0[1+j], s);
            s = fmaf(c[j][7], t3[4+j], s);
            s = fmaf(c[j][8], t3[1+j], s);
            acc[j] = fmaf(-ev[j], s, acc[j]);
        }
    };

    // 1-ahead register pipeline over EC e-planes, unrolled x2 (no reg copies)
    TT ta, tc;
    LD(ta, e0);
    #pragma unroll 1
    for (int ei = 0; ei < EC-2; ei += 2){
        LD(tc, e0+ei+1);
        CMP(ta);
        LD(ta, e0+ei+2);
        CMP(tc);
    }
    LD(tc, e0+EC-1);
    CMP(ta);
    CMP(tc);

    float part = acc[0] + acc[1] + acc[2] + acc[3];
    for (int s = 32; s; s >>= 1) part += __shfl_xor(part, s);
    __shared__ float sp[8];
    if (ln == 0) sp[wv] = part;
    __syncthreads();
    if (tid == 0){
        float bs = 0.f;
        #pragma unroll
        for (int v = 0; v < 8; v++) bs += sp[v];
        double* accp = (double*)(ws + WS_ACC);
        atomicAdd(accp, (double)bs);
        __threadfence();
        unsigned int done = atomicAdd((unsigned int*)(ws + WS_CNT), 1u);
        if (done == gridDim.x - 1){
            double v = atomicAdd(accp, 0.0);
            out[0] = (float)(v / (double)((size_t)Bb * PLANE));
        }
    }
}

extern "C" void kernel_launch(void* const* d_in, const int* in_sizes, int n_in,
                              void* d_out, int out_size, void* d_ws, size_t ws_size,
                              hipStream_t stream) {
    const float* embeds = (const float*)d_in[0];   // [4,32,512,512]
    const float* tf     = (const float*)d_in[1];   // [4,32,512,512]
    const float* raw    = (const float*)d_in[2];   // [1,1,512,512]
    const float* mask   = (const float*)d_in[3];   // [1,9,512,512]
    float* ws  = (float*)d_ws;
    float* out = (float*)d_out;

    k_blur  <<<256, 256, 0, stream>>>(raw, ws);
    k_minmax<<<PLANE/512, 512, 0, stream>>>(ws);
    k_main  <<<2048, 512, 0, stream>>>(embeds, tf, mask, ws, out);
}

// Round 10
// 89.274 us; speedup vs baseline: 2.6236x; 1.7473x over previous
//
#include <hip/hip_runtime.h>
#include <math.h>

#define Hh 512
#define Ww 512
#define Bb 4
#define Ee 32
#define PLANE (Hh*Ww)        // 262144
#define NOFF 9
#define BUFF 5632            // floats per LDS buffer: T 7*512 + E 4*512

// ws layout (float indices)
#define WS_BLUR   0
#define WS_MIN    524304
#define WS_MAX    524320
#define WS_ACC    524336
#define WS_CNT    524338

__device__ __constant__ int d_OH[NOFF] = {0,-1,-1,0,-2,-2,0,-3,-3};
__device__ __constant__ int d_OW[NOFF] = {-1,0,-1,-2,0,-2,-3,0,-3};

__device__ __forceinline__ void gload_lds16(const float* g, float* l){
    __builtin_amdgcn_global_load_lds(
        (const __attribute__((address_space(1))) void*)g,
        (__attribute__((address_space(3))) void*)l, 16, 0, 0);
}

#define WAITV(n) asm volatile("s_waitcnt vmcnt(" #n ")" ::: "memory")
#define SCB()    __builtin_amdgcn_sched_barrier(0)
#define RBAR()   __builtin_amdgcn_s_barrier()

// ---- fused 2D gaussian blur (sigma=1.2, r=5, edge-clamped), 32x32 tiles + halo
#define TS 32
#define HALO 5
__global__ __launch_bounds__(256) void k_blur(const float* __restrict__ raw,
                                              float* __restrict__ ws){
    __shared__ float sraw[TS+2*HALO][TS+2*HALO+1];
    __shared__ float shb [TS][TS+2*HALO+1];
    int tx = blockIdx.x & 15, ty = blockIdx.x >> 4;
    int r0 = ty*TS - HALO, c0 = tx*TS - HALO;

    double kd[11], s = 0.0;
    #pragma unroll
    for (int i = 0; i < 11; i++){
        double x = (double)(i - 5) / 1.2;
        kd[i] = exp(-0.5 * x * x);
        s += kd[i];
    }
    float w[11];
    #pragma unroll
    for (int i = 0; i < 11; i++) w[i] = (float)(kd[i] / s);

    for (int t = threadIdx.x; t < 42*42; t += 256){
        int rr = t / 42, cc = t - rr*42;
        int gr = min(max(r0+rr, 0), Hh-1);
        int gc = min(max(c0+cc, 0), Ww-1);
        sraw[rr][cc] = raw[gr*Ww + gc];
    }
    __syncthreads();
    for (int t = threadIdx.x; t < TS*42; t += 256){
        int rr = t / 42, cc = t - rr*42;
        float a = 0.f;
        #pragma unroll
        for (int i = 0; i < 11; i++) a += w[i] * sraw[rr+i][cc];
        shb[rr][cc] = a;
    }
    __syncthreads();
    for (int t = threadIdx.x; t < TS*TS; t += 256){
        int rr = t >> 5, cc = t & 31;
        float a = 0.f;
        #pragma unroll
        for (int i = 0; i < 11; i++) a += w[i] * shb[rr][cc+i];
        ws[WS_BLUR + (ty*TS+rr)*Ww + (tx*TS+cc)] = a;
    }
    if (blockIdx.x == 0){
        if (threadIdx.x < 16){
            ((unsigned int*)(ws + WS_MIN))[threadIdx.x] = 0x7F800000u;
            ((unsigned int*)(ws + WS_MAX))[threadIdx.x] = 0u;
        }
        if (threadIdx.x == 0){
            *(double*)(ws + WS_ACC) = 0.0;
            *(unsigned int*)(ws + WS_CNT) = 0u;
        }
    }
}

// per-offset min/max of d_i = |blur - rolled blur|
__global__ void k_minmax(float* __restrict__ ws){
    int idx = blockIdx.x * 512 + threadIdx.x;
    int h = idx >> 9, w = idx & 511;
    float bc = ws[WS_BLUR + idx];
    int lane = threadIdx.x & 63, wv = threadIdx.x >> 6;
    __shared__ float smn[8 * NOFF], smx[8 * NOFF];
    #pragma unroll
    for (int i = 0; i < NOFF; i++){
        int hn = (h + d_OH[i]) & (Hh-1);
        int wn = (w + d_OW[i]) & (Ww-1);
        float d = fabsf(bc - ws[WS_BLUR + hn * Ww + wn]);
        float mnv = d, mxv = d;
        for (int s = 32; s; s >>= 1){
            mnv = fminf(mnv, __shfl_xor(mnv, s));
            mxv = fmaxf(mxv, __shfl_xor(mxv, s));
        }
        if (lane == 0){ smn[wv * NOFF + i] = mnv; smx[wv * NOFF + i] = mxv; }
    }
    __syncthreads();
    if (threadIdx.x < NOFF){
        float mnv = smn[threadIdx.x], mxv = smx[threadIdx.x];
        for (int v = 1; v < 8; v++){
            mnv = fminf(mnv, smn[v * NOFF + threadIdx.x]);
            mxv = fmaxf(mxv, smx[v * NOFF + threadIdx.x]);
        }
        atomicMin((unsigned int*)(ws + WS_MIN) + threadIdx.x, __float_as_uint(mnv));
        atomicMax((unsigned int*)(ws + WS_MAX) + threadIdx.x, __float_as_uint(mxv));
    }
}

// fused loss: 512-thr block = 4 rows x 512 cols of one batch, all 32 e-planes.
// LDS pipeline: 4 buffers, depth-2 prefetch, counted vmcnt + raw s_barrier.
// Per plane: 22 gload_lds chunks (T rows h-3..h+3: 14, E rows h..h+3: 8).
__global__ __launch_bounds__(512)
void k_main(const float* __restrict__ E, const float* __restrict__ T,
            const float* __restrict__ mask, float* __restrict__ ws,
            float* __restrict__ out){
    __shared__ float sL[4*BUFF];
    __shared__ float sp[8];

    int blk = blockIdx.x;             // 0..511
    int bb  = blk >> 7;               // batch
    int rg  = blk & 127;
    int row4 = rg << 2;

    int tid = threadIdx.x;
    int rq  = tid >> 7;               // 0..3
    int wq  = tid & 127;
    int wv  = tid >> 6;               // wave 0..7
    int ln  = tid & 63;
    int hr  = row4 + rq;
    int c0  = wq << 2;
    int cl  = (c0 - 4) & 511;
    int pix = hr * Ww + c0;

    // ---- per-pixel coefficients c[j][i] from blurred raw + mask (prologue vmem)
    const float* bl = ws + WS_BLUR;
    float tb[4][8];
    #pragma unroll
    for (int r = 0; r < 4; r++){
        int rr = (hr - r) & 511;
        float4 l4 = *(const float4*)(bl + rr*Ww + cl);
        float4 o4 = *(const float4*)(bl + rr*Ww + c0);
        tb[r][0]=l4.x; tb[r][1]=l4.y; tb[r][2]=l4.z; tb[r][3]=l4.w;
        tb[r][4]=o4.x; tb[r][5]=o4.y; tb[r][6]=o4.z; tb[r][7]=o4.w;
    }
    const unsigned int* mnb = (const unsigned int*)(ws + WS_MIN);
    const unsigned int* mxb = (const unsigned int*)(ws + WS_MAX);
    float mn[NOFF], inv[NOFF];
    #pragma unroll
    for (int i = 0; i < NOFF; i++){
        mn[i]  = __uint_as_float(mnb[i]);
        inv[i] = 1.f / (__uint_as_float(mxb[i]) - mn[i]);
    }
    float c[4][NOFF];
    float acc[4];
    #pragma unroll
    for (int j = 0; j < 4; j++){
        float bc = tb[0][4+j];
        float d[NOFF];
        d[0] = fabsf(bc - tb[0][3+j]);
        d[1] = fabsf(bc - tb[1][4+j]);
        d[2] = fabsf(bc - tb[1][3+j]);
        d[3] = fabsf(bc - tb[0][2+j]);
        d[4] = fabsf(bc - tb[2][4+j]);
        d[5] = fabsf(bc - tb[2][2+j]);
        d[6] = fabsf(bc - tb[0][1+j]);
        d[7] = fabsf(bc - tb[3][4+j]);
        d[8] = fabsf(bc - tb[3][1+j]);
        acc[j] = 0.f;
        #pragma unroll
        for (int i = 0; i < NOFF; i++){
            float a = (d[i] - mn[i]) * inv[i];
            float mv = ((const float*)(mask + i * PLANE + pix))[j];
            c[j][i] = mv * (0.5f - a);
            acc[j] += c[j][i];
        }
    }

    // ---- per-wave staging chunk setup: chunks {wv, wv+8, wv+16(if wv<6)}
    // chunk t<14: T row t>>1 (tile rows 0..6 = image rows row4-3..row4+3), half t&1
    // chunk t>=14: E row (t-14)>>1 (image rows row4..row4+3), half (t-14)&1
    const float* Tbase = T + (size_t)bb * Ee * PLANE;
    const float* Ebase = E + (size_t)bb * Ee * PLANE;
    const float* gp0; const float* gp1; const float* gp2 = 0;
    int lo0, lo1, lo2 = 0;
    {
        int ch0 = wv, ch1 = wv + 8, ch2 = wv + 16;
        // ch0 is always a T chunk (0..7)
        {
            int r = ch0 >> 1, hf = (ch0 & 1) << 8;
            gp0 = Tbase + ((row4 - 3 + r) & 511)*Ww + hf + ln*4;
            lo0 = r*512 + hf + ln*4;
        }
        if (ch1 < 14){
            int r = ch1 >> 1, hf = (ch1 & 1) << 8;
            gp1 = Tbase + ((row4 - 3 + r) & 511)*Ww + hf + ln*4;
            lo1 = r*512 + hf + ln*4;
        } else {
            int t2 = ch1 - 14, r = t2 >> 1, hf = (t2 & 1) << 8;
            gp1 = Ebase + (row4 + r)*Ww + hf + ln*4;
            lo1 = 7*512 + r*512 + hf + ln*4;
        }
        if (wv < 6){
            int t2 = ch2 - 14, r = t2 >> 1, hf = (t2 & 1) << 8;
            gp2 = Ebase + (row4 + r)*Ww + hf + ln*4;
            lo2 = 7*512 + r*512 + hf + ln*4;
        }
    }

    #define STG(bi, k) do { \
        size_t ko = (size_t)(k) * PLANE; \
        float* lb = sL + (bi)*BUFF; \
        gload_lds16(gp0 + ko, lb + lo0); \
        gload_lds16(gp1 + ko, lb + lo1); \
        if (wv < 6) gload_lds16(gp2 + ko, lb + lo2); \
    } while(0)

    #define CMPB(bi) do { \
        const float* tT = sL + (bi)*BUFF; \
        const float* tE = tT + 7*512; \
        float4 ev4 = *(const float4*)(tE + rq*512 + c0); \
        float s0, s1, s2, s3; \
        { const float* rp = tT + (3 + rq) * 512; \
          float4 l4 = *(const float4*)(rp + cl); \
          float4 o4 = *(const float4*)(rp + c0); \
          float t[8] = {l4.x,l4.y,l4.z,l4.w, o4.x,o4.y,o4.z,o4.w}; \
          s0 = c[0][0]*t[3]; s0 = fmaf(c[0][3], t[2], s0); s0 = fmaf(c[0][6], t[1], s0); \
          s1 = c[1][0]*t[4]; s1 = fmaf(c[1][3], t[3], s1); s1 = fmaf(c[1][6], t[2], s1); \
          s2 = c[2][0]*t[5]; s2 = fmaf(c[2][3], t[4], s2); s2 = fmaf(c[2][6], t[3], s2); \
          s3 = c[3][0]*t[6]; s3 = fmaf(c[3][3], t[5], s3); s3 = fmaf(c[3][6], t[4], s3); } \
        { const float* rp = tT + (2 + rq) * 512; \
          float4 l4 = *(const float4*)(rp + cl); \
          float4 o4 = *(const float4*)(rp + c0); \
          float t[8] = {l4.x,l4.y,l4.z,l4.w, o4.x,o4.y,o4.z,o4.w}; \
          s0 = fmaf(c[0][1], t[4], s0); s0 = fmaf(c[0][2], t[3], s0); \
          s1 = fmaf(c[1][1], t[5], s1); s1 = fmaf(c[1][2], t[4], s1); \
          s2 = fmaf(c[2][1], t[6], s2); s2 = fmaf(c[2][2], t[5], s2); \
          s3 = fmaf(c[3][1], t[7], s3); s3 = fmaf(c[3][2], t[6], s3); } \
        { const float* rp = tT + (1 + rq) * 512; \
          float4 l4 = *(const float4*)(rp + cl); \
          float4 o4 = *(const float4*)(rp + c0); \
          float t[8] = {l4.x,l4.y,l4.z,l4.w, o4.x,o4.y,o4.z,o4.w}; \
          s0 = fmaf(c[0][4], t[4], s0); s0 = fmaf(c[0][5], t[2], s0); \
          s1 = fmaf(c[1][4], t[5], s1); s1 = fmaf(c[1][5], t[3], s1); \
          s2 = fmaf(c[2][4], t[6], s2); s2 = fmaf(c[2][5], t[4], s2); \
          s3 = fmaf(c[3][4], t[7], s3); s3 = fmaf(c[3][5], t[5], s3); } \
        { const float* rp = tT + (0 + rq) * 512; \
          float4 l4 = *(const float4*)(rp + cl); \
          float4 o4 = *(const float4*)(rp + c0); \
          float t[8] = {l4.x,l4.y,l4.z,l4.w, o4.x,o4.y,o4.z,o4.w}; \
          s0 = fmaf(c[0][7], t[4], s0); s0 = fmaf(c[0][8], t[1], s0); \
          s1 = fmaf(c[1][7], t[5], s1); s1 = fmaf(c[1][8], t[2], s1); \
          s2 = fmaf(c[2][7], t[6], s2); s2 = fmaf(c[2][8], t[3], s2); \
          s3 = fmaf(c[3][7], t[7], s3); s3 = fmaf(c[3][8], t[4], s3); } \
        acc[0] = fmaf(-ev4.x, s0, acc[0]); \
        acc[1] = fmaf(-ev4.y, s1, acc[1]); \
        acc[2] = fmaf(-ev4.z, s2, acc[2]); \
        acc[3] = fmaf(-ev4.w, s3, acc[3]); \
    } while(0)

    // drain all prologue vmem so vmcnt counts only staging loads
    WAITV(0); SCB();

    // depth-2 prologue
    STG(0, 0);
    STG(1, 1);

    // main loop: planes 0..29; counted waits keep 2 planes in flight
    #pragma unroll 1
    for (int k = 0; k < 30; k++){
        STG((k + 2) & 3, k + 2);
        if (wv < 6) { WAITV(6); } else { WAITV(4); }
        SCB();
        RBAR();
        SCB();
        CMPB(k & 3);
    }
    // k=30: no stage; wait own n_w (plane 31 still in flight)
    if (wv < 6) { WAITV(3); } else { WAITV(2); }
    SCB();
    RBAR();
    SCB();
    CMPB(30 & 3);
    // k=31: drain
    WAITV(0);
    SCB();
    RBAR();
    SCB();
    CMPB(31 & 3);

    float part = acc[0] + acc[1] + acc[2] + acc[3];
    for (int s = 32; s; s >>= 1) part += __shfl_xor(part, s);
    if (ln == 0) sp[wv] = part;
    __syncthreads();
    if (tid == 0){
        float bs = 0.f;
        #pragma unroll
        for (int v = 0; v < 8; v++) bs += sp[v];
        double* accp = (double*)(ws + WS_ACC);
        atomicAdd(accp, (double)bs);
        __threadfence();
        unsigned int done = atomicAdd((unsigned int*)(ws + WS_CNT), 1u);
        if (done == gridDim.x - 1){
            double v = atomicAdd(accp, 0.0);
            out[0] = (float)(v / (double)((size_t)Bb * PLANE));
        }
    }
}

extern "C" void kernel_launch(void* const* d_in, const int* in_sizes, int n_in,
                              void* d_out, int out_size, void* d_ws, size_t ws_size,
                              hipStream_t stream) {
    const float* embeds = (const float*)d_in[0];   // [4,32,512,512]
    const float* tf     = (const float*)d_in[1];   // [4,32,512,512]
    const float* raw    = (const float*)d_in[2];   // [1,1,512,512]
    const float* mask   = (const float*)d_in[3];   // [1,9,512,512]
    float* ws  = (float*)d_ws;
    float* out = (float*)d_out;

    k_blur  <<<256, 256, 0, stream>>>(raw, ws);
    k_minmax<<<PLANE/512, 512, 0, stream>>>(ws);
    k_main  <<<512, 512, 0, stream>>>(embeds, tf, mask, ws, out);
}